// Round 9
// baseline (248.898 us; speedup 1.0000x reference)
//
#include <hip/hip_runtime.h>

#define NB 1024
#define NS 1024
#define NT 32
#define L2E 1.44269504088896340736f
#define LN2 0.69314718055994530942f

typedef short        bfrag  __attribute__((ext_vector_type(8)));   // 8 bf16 (4 VGPR)
typedef float        cfrag  __attribute__((ext_vector_type(16)));  // 16 f32 acc
typedef __bf16       bf16x2 __attribute__((ext_vector_type(2)));
typedef float        f32x8  __attribute__((ext_vector_type(8)));
typedef float        f32x4  __attribute__((ext_vector_type(4)));
typedef float        f32x2  __attribute__((ext_vector_type(2)));
typedef unsigned int u32;
typedef unsigned int u32x4  __attribute__((ext_vector_type(4)));

__device__ __forceinline__ float fexp2(float x){ return __builtin_amdgcn_exp2f(x); }
__device__ __forceinline__ float flog2(float x){ return __builtin_amdgcn_logf(x); }

// RNE pack (prologue only)
__device__ __forceinline__ u32 pkbf_rne(float a, float b){
    f32x2 t; t.x = a; t.y = b;
    return __builtin_bit_cast(u32, __builtin_convertvector(t, bf16x2));
}
// truncation pack: single v_perm_b32. low16 = bf16_trunc(a), high16 = bf16_trunc(b).
__device__ __forceinline__ u32 pkbf_t(float a, float b){
    return __builtin_amdgcn_perm(__builtin_bit_cast(u32, b),
                                 __builtin_bit_cast(u32, a), 0x07060302u);
}
__device__ __forceinline__ bfrag mk_afrag(f32x8 v){
    u32x4 r;
    r[0] = pkbf_rne(v[0], v[1]); r[1] = pkbf_rne(v[2], v[3]);
    r[2] = pkbf_rne(v[4], v[5]); r[3] = pkbf_rne(v[6], v[7]);
    return __builtin_bit_cast(bfrag, r);
}
// wave-uniform power-of-2 exponent extract (clamped)
__device__ __forceinline__ int exref(float ref){
    u32 xb = __builtin_bit_cast(u32, ref);
    u32 xf = __builtin_amdgcn_readfirstlane(xb);
    int ex = (int)((xf >> 23) & 0xFFu) - 127;
    return ex < -120 ? -120 : (ex > 120 ? 120 : ex);
}

// row-space involution applied implicitly by packing C/D straight into B regs:
// swaps row blocks [4..7]<->[8..11] and [20..23]<->[24..27].
__device__ __forceinline__ int rho(int k){
    int bb = (k >> 2) & 3;
    return (bb == 1 || bb == 2) ? (k ^ 12) : k;
}

template<int N> struct ic { static constexpr int value = N; };
union accu { cfrag c; f32x2 p[8]; };
union q4u  { f32x4 v; f32x2 p[2]; };

#define MFMA(A,B,C) __builtin_amdgcn_mfma_f32_32x32x16_bf16( \
    (A), __builtin_bit_cast(bfrag, B), (C), 0, 0, 0)

// ---------------- Phase 1: per-(batch,chunk) transfer matrix + gold ----------
// r6 single-chain loop, regeometried: 128-thread blocks (2 waves) x 4096 so the
// dispatcher can pack ~16 blocks/CU (target 8 waves/SIMD resident vs r6's ~4.5 —
// the r6/r7 invariance showed the kernel is concurrency-starved: all pipes <50%,
// same perf at 4.5 and 5.4 effective chains/SIMD).
// Diet: mid-group (i==3) renorm dropped — unrenormed 8-step drift <= ~2^80, safe
// in f32/bf16 (max 2^127); the group-end renorm still folds free into the next
// commit.
__global__ __launch_bounds__(128, 8) void crf_chunk(
    const float* __restrict__ logits, const float* __restrict__ trans,
    const int* __restrict__ tags, const int* __restrict__ lens,
    u32* __restrict__ wmat, float* __restrict__ woff,
    float* __restrict__ gpart, float* __restrict__ outz)
{
    __shared__ __align__(16) float dscall[2 * 512];   // per-wave: 2 bufs x 8 steps x 32

    const int tid = threadIdx.x;
    const int wv  = tid >> 6, lt = tid & 63;
    const int m   = lt & 31,  h  = lt >> 5;
    const int bc  = blockIdx.x * 2 + wv;
    const int b   = bc >> 3,  c  = bc & 7;
    float* dsc = dscall + wv * 512;

    if (blockIdx.x == 0 && tid == 0) *outz = 0.0f;    // replaces memset dispatch

    const float* base = logits + (size_t)b * NS * NT;
    const int    len  = lens[b];
    const int    tb   = b * NS;

    // A frags with rho-compensated k index: A'[m][k] = exp(trans[rho(k)][m])
    f32x8 Et0, Et1;
    #pragma unroll
    for (int j = 0; j < 8; j++){
        Et0[j] = fexp2(L2E * trans[rho(     8*h + j)*NT + m]);
        Et1[j] = fexp2(L2E * trans[rho(16 + 8*h + j)*NT + m]);
    }
    const bfrag A0f = mk_afrag(Et0);
    const bfrag A1f = mk_afrag(Et1);

    // B = rho-permuted identity (packed bf16): slot k holds row rho(k)
    u32x4 B0v, B1v;
    #pragma unroll
    for (int d = 0; d < 4; d++){
        int k0 = 8*h + 2*d;      u32 v = 0;
        if (rho(k0)     == m) v |= 0x3F80u;
        if (rho(k0 + 1) == m) v |= 0x3F800000u;
        B0v[d] = v;
        int k1 = 16 + 8*h + 2*d; v = 0;
        if (rho(k1)     == m) v |= 0x3F80u;
        if (rho(k1 + 1) == m) v |= 0x3F800000u;
        B1v[d] = v;
    }

    cfrag zacc;
    #pragma unroll
    for (int q = 0; q < 16; q++) zacc[q] = 0.0f;

    int   offi = 0;        // accumulated log2 scale (integer, wave-uniform)
    float exf  = 0.0f;     // deferred scale folded into next block's step-0 D
    const int tbeg = c*128 + 1;

    float eA[4], eB[4];

    auto issue = [&](float (&e)[4], int k){
        const int t0 = tbeg + k*8 + 4*h;
        #pragma unroll
        for (int i = 0; i < 4; i++){
            int t = t0 + i; t = t > (NS-1) ? (NS-1) : t;   // clamp c==7 tail
            e[i] = base[t*NT + m];
        }
    };
    auto commit = [&](float (&e)[4], int k){
        float* sp = dsc + (k & 1)*256 + (4*h)*32 + m;
        float a0 = (h == 0) ? -exf : 0.0f;
        sp[0]    = fexp2(fmaf(L2E, e[0], a0));
        sp[32]   = fexp2(L2E * e[1]);
        sp[64]   = fexp2(L2E * e[2]);
        sp[96]   = fexp2(L2E * e[3]);
    };

    auto procN = [&](int k, bool defer, auto nstc){
        constexpr int NST = decltype(nstc)::value;
        const float* db = dsc + (k & 1)*256 + 4*h;
        #pragma unroll
        for (int i = 0; i < NST; i++){
            accu acc;
            acc.c = MFMA(A0f, B0v, zacc);
            acc.c = MFMA(A1f, B1v, acc.c);

            // D_t row scales (true row space; unaffected by rho)
            q4u d0, d1, d2, d3;
            d0.v = *(const f32x4*)(db + i*32 +  0);
            d1.v = *(const f32x4*)(db + i*32 +  8);
            d2.v = *(const f32x4*)(db + i*32 + 16);
            d3.v = *(const f32x4*)(db + i*32 + 24);
            acc.p[0] *= d0.p[0]; acc.p[1] *= d0.p[1];
            acc.p[2] *= d1.p[0]; acc.p[3] *= d1.p[1];
            acc.p[4] *= d2.p[0]; acc.p[5] *= d2.p[1];
            acc.p[6] *= d3.p[0]; acc.p[7] *= d3.p[1];

            // group-end renorm only (mid-group dropped: f32/bf16 range absorbs
            // <= ~2^80 intra-group drift; scale application folds free into the
            // next commit's exp2 argument)
            if (i == 7 && defer){
                int ex = exref(fmaxf(acc.c[0], acc.c[8]));
                offi += ex;
                exf = (float)ex;
            }

            // pack C/D straight into B regs (lane-local; applies rho implicitly)
            B0v[0] = pkbf_t(acc.c[0],  acc.c[1]);  B0v[1] = pkbf_t(acc.c[2],  acc.c[3]);
            B0v[2] = pkbf_t(acc.c[4],  acc.c[5]);  B0v[3] = pkbf_t(acc.c[6],  acc.c[7]);
            B1v[0] = pkbf_t(acc.c[8],  acc.c[9]);  B1v[1] = pkbf_t(acc.c[10], acc.c[11]);
            B1v[2] = pkbf_t(acc.c[12], acc.c[13]); B1v[3] = pkbf_t(acc.c[14], acc.c[15]);
        }
    };

    issue(eA, 0); commit(eA, 0);
    #pragma unroll 1
    for (int k = 0; k < 14; k += 2){
        issue(eB, k + 1);
        procN(k, true, ic<8>{});
        commit(eB, k + 1);
        issue(eA, k + 2);
        procN(k + 1, true, ic<8>{});
        commit(eA, k + 2);
    }
    issue(eB, 15);
    procN(14, true, ic<8>{});
    commit(eB, 15);
    if (c != 7) procN(15, false, ic<8>{});   // wave-uniform branch
    else        procN(15, false, ic<7>{});   // chunk 7 has 127 steps

    // ---- store frag contiguously per lane: wmat[bc*512 + lt*8 + d] (2x dwordx4)
    {
        u32* wp = wmat + (size_t)bc * 512 + (size_t)lt * 8;
        *(u32x4*)(wp)     = B0v;
        *(u32x4*)(wp + 4) = B1v;
    }
    if (lt == 0) woff[bc] = (float)offi;

    // ---- gold for this chunk's 128 positions (t = tbeg..tbeg+127), 2/lane.
    {
        const int t1 = tbeg + 2*lt;
        const int t2 = t1 + 1;
        const int i2 = t2 > (NS-1) ? (NS-1) : t2;   // c==7,lt==63: t2==1024
        const int g0 = tags[tb + t1 - 1];
        const int g1 = tags[tb + t1];
        const int g2 = tags[tb + i2];
        float gg = 0.0f;
        if (t1 < len) gg += base[t1*NT + g1] + trans[g0*NT + g1];
        if (t2 < len) gg += base[t2*NT + g2] + trans[g1*NT + g2];
        #pragma unroll
        for (int d = 1; d < 64; d <<= 1) gg += __shfl_xor(gg, d, 64);
        if (lt == 0){
            if (c == 0) gg += base[tags[tb]];        // t=0 emission
            gpart[bc] = gg;                          // plain store, no atomic
        }
    }
}

// ---------------- Phase 2: per-batch MFMA matrix-chain combine ----------------
// UNCHANGED from round 6 (verified).
__global__ __launch_bounds__(256) void crf_combine(
    const float* __restrict__ logits,
    const u32* __restrict__ wmat, const float* __restrict__ woff,
    const float* __restrict__ gpart, float* __restrict__ out)
{
    const int tid = threadIdx.x;
    const int wv  = tid >> 6, lt = tid & 63;
    const int m   = lt & 31,  h  = lt >> 5;
    const int b   = blockIdx.x * 4 + wv;
    const float* base = logits + (size_t)b * NS * NT;

    uint4 mf[16];
    const u32* wb = wmat + (size_t)b * 8 * 512 + (size_t)lt * 8;
    #pragma unroll
    for (int j = 0; j < 8; j++){
        mf[2*j]     = *(const uint4*)(wb + j*512);
        mf[2*j + 1] = *(const uint4*)(wb + j*512 + 4);
    }

    float4 gp0 = ((const float4*)(gpart + b*8))[0];
    float4 gp1 = ((const float4*)(gpart + b*8))[1];
    const float gold = (gp0.x + gp0.y) + (gp0.z + gp0.w)
                     + (gp1.x + gp1.y) + (gp1.z + gp1.w);

    float voff = 0.0f;
    #pragma unroll
    for (int cc = 0; cc < 8; cc++) voff += woff[b*8 + cc];

    u32x4 S0, S1;
    #pragma unroll
    for (int d = 0; d < 4; d++){
        int k0 = 8*h + 2*d;      u32 v = 0;
        if (rho(k0)     == m) v |= 0x3F80u;
        if (rho(k0 + 1) == m) v |= 0x3F800000u;
        S0[d] = v;
        int k1 = 16 + 8*h + 2*d; v = 0;
        if (rho(k1)     == m) v |= 0x3F80u;
        if (rho(k1 + 1) == m) v |= 0x3F800000u;
        S1[d] = v;
    }

    cfrag zacc;
    #pragma unroll
    for (int q = 0; q < 16; q++) zacc[q] = 0.0f;

    #pragma unroll
    for (int j = 7; j >= 0; j--){
        accu acc;
        acc.c = MFMA(__builtin_bit_cast(bfrag, mf[2*j]),     S0, zacc);
        acc.c = MFMA(__builtin_bit_cast(bfrag, mf[2*j + 1]), S1, acc.c);

        float mx = acc.c[0];
        #pragma unroll
        for (int q = 1; q < 16; q++) mx = fmaxf(mx, acc.c[q]);
        #pragma unroll
        for (int d = 1; d < 64; d <<= 1) mx = fmaxf(mx, __shfl_xor(mx, d, 64));
        int ex = exref(mx);
        float sc = __builtin_bit_cast(float, (u32)(127 - ex) << 23);
        #pragma unroll
        for (int q = 0; q < 16; q++) acc.c[q] *= sc;
        voff += (float)ex;

        S0[0] = pkbf_t(acc.c[0],  acc.c[1]);  S0[1] = pkbf_t(acc.c[2],  acc.c[3]);
        S0[2] = pkbf_t(acc.c[4],  acc.c[5]);  S0[3] = pkbf_t(acc.c[6],  acc.c[7]);
        S1[0] = pkbf_t(acc.c[8],  acc.c[9]);  S1[1] = pkbf_t(acc.c[10], acc.c[11]);
        S1[2] = pkbf_t(acc.c[12], acc.c[13]); S1[3] = pkbf_t(acc.c[14], acc.c[15]);
    }

    u32x4 V0, V1;
    #pragma unroll
    for (int d = 0; d < 4; d++){
        int k0 = 8*h + 2*d;
        V0[d] = pkbf_rne(fexp2(L2E * base[rho(k0)]), fexp2(L2E * base[rho(k0+1)]));
        int k1 = 16 + 8*h + 2*d;
        V1[d] = pkbf_rne(fexp2(L2E * base[rho(k1)]), fexp2(L2E * base[rho(k1+1)]));
    }

    accu fin;
    fin.c = MFMA(__builtin_bit_cast(bfrag, S0), V0, zacc);
    fin.c = MFMA(__builtin_bit_cast(bfrag, S1), V1, fin.c);

    float s = 0.0f;
    #pragma unroll
    for (int q = 0; q < 16; q++) s += fin.c[q];
    s += __shfl_xor(s, 32, 64);

    if (lt == 0){
        float logz = LN2 * (voff + flog2(s));
        atomicAdd(out, (logz - gold) * (1.0f / (float)NB));
    }
}

extern "C" void kernel_launch(void* const* d_in, const int* in_sizes, int n_in,
                              void* d_out, int out_size, void* d_ws, size_t ws_size,
                              hipStream_t stream) {
    const float* logits = (const float*)d_in[0];
    const float* trans  = (const float*)d_in[1];
    const int*   tags   = (const int*)d_in[2];
    const int*   lens   = (const int*)d_in[3];

    u32*   wmat  = (u32*)d_ws;                                   // 16 MB
    float* woff  = (float*)((char*)d_ws + 16u*1024u*1024u);      // 32 KB
    float* gpart = woff + 8192;                                  // 32 KB

    crf_chunk  <<<4096, 128, 0, stream>>>(logits, trans, tags, lens,
                                          wmat, woff, gpart, (float*)d_out);
    crf_combine<<< 256, 256, 0, stream>>>(logits, wmat, woff, gpart,
                                          (float*)d_out);
}